// Round 2
// baseline (74.711 us; speedup 1.0000x reference)
//
#include <hip/hip_runtime.h>
#include <cstddef>
#include <cstdint>

#define NROWS 200000
#define CIN   32
#define COUT  64
#define KV    27

typedef __attribute__((ext_vector_type(8))) short  short8;
typedef __attribute__((ext_vector_type(4))) float  f32x4;

// RNE float -> bf16 (inputs finite)
__device__ __forceinline__ unsigned short f2bf(float x) {
  unsigned u = __builtin_bit_cast(unsigned, x);
  u += 0x7FFFu + ((u >> 16) & 1u);
  return (unsigned short)(u >> 16);
}

// Pack weight [27][32][64] f32 -> bf16 B-fragments, mfma_16x16x32 B layout:
// wsB[(k*4+t)*64 + lane][f] = W[k][(lane>>4)*8+f][t*16+(lane&15)]
__global__ void prep_weight_kernel(const float* __restrict__ w,
                                   short8* __restrict__ wsB) {
  int tid = blockIdx.x * blockDim.x + threadIdx.x;   // 27*4*64 = 6912
  if (tid >= KV * 4 * 64) return;
  int lane = tid & 63;
  int t    = (tid >> 6) & 3;
  int k    = tid >> 8;
  int col  = t * 16 + (lane & 15);
  int kin0 = (lane >> 4) * 8;
  short8 v;
#pragma unroll
  for (int f = 0; f < 8; ++f)
    v[f] = (short)f2bf(w[((size_t)k * CIN + kin0 + f) * COUT + col]);
  wsB[tid] = v;
}

// feats f32 [N][32] -> bf16 [N+1][32]; row N (pad) = zeros.
__global__ void prep_feats_kernel(const float* __restrict__ feats,
                                  short8* __restrict__ fb) {
  int i = blockIdx.x * blockDim.x + threadIdx.x;
  const int total8 = (NROWS + 1) * CIN / 8;          // 800004
  if (i >= total8) return;
  short8 v = {0, 0, 0, 0, 0, 0, 0, 0};
  if (i < NROWS * CIN / 8) {
    const f32x4* p = (const f32x4*)feats + (size_t)i * 2;
    f32x4 a = p[0], b = p[1];
#pragma unroll
    for (int f = 0; f < 4; ++f) {
      v[f]     = (short)f2bf(a[f]);
      v[4 + f] = (short)f2bf(b[f]);
    }
  }
  fb[i] = v;
}

// Main: 1024-thread block = 16 waves. All 27x4 B-fragments staged in LDS once
// (110,592 B, 1 block/CU -> 16 waves/CU). Each wave: one 16-row M-tile x
// COUT=64. k-loop software-pipelined: idx 2 ahead, gather 1 ahead.
__global__ __launch_bounds__(1024, 4)
void spconv_mfma_kernel(const unsigned short* __restrict__ featsbf,
                        const short8* __restrict__ wsB,
                        const float* __restrict__ bias,
                        const int* __restrict__ in_idx,
                        float* __restrict__ out) {
  __shared__ short8 sB[KV * 4 * 64];                 // 110,592 bytes

  const int tid = threadIdx.x;
  for (int i = tid; i < KV * 4 * 64; i += 1024) sB[i] = wsB[i];
  __syncthreads();

  const int lane = tid & 63;
  const int wid  = (int)((blockIdx.x * 1024 + tid) >> 6);  // global wave id
  const int row0 = wid * 16;
  if (row0 >= NROWS) return;
  const int c16 = lane & 15;
  const int kg  = lane >> 4;

  f32x4 acc[4];                                       // [n-tile]
#pragma unroll
  for (int t = 0; t < 4; ++t) {
    float bv = bias[t * 16 + c16];
    f32x4 bvv = {bv, bv, bv, bv};
    acc[t] = bvv;
  }

  const int* idxp = in_idx + row0 + c16;
  const unsigned short* fb = featsbf;
  const int koff = kg * 8;

  // pipeline prologue
  int idA = idxp[0];                                  // idx for k=0
  int idB = idxp[(size_t)1 * NROWS];                  // idx for k=1
  short8 af = *(const short8*)(fb + (size_t)idA * CIN + koff);

  for (int k = 0; k < KV; ++k) {
    const int kk2 = (k + 2 < KV) ? k + 2 : KV - 1;    // clamp: harmless re-read
    int idC = idxp[(size_t)kk2 * NROWS];
    short8 afn = *(const short8*)(fb + (size_t)idB * CIN + koff);

    short8 b0 = sB[(k * 4 + 0) * 64 + lane];
    short8 b1 = sB[(k * 4 + 1) * 64 + lane];
    short8 b2 = sB[(k * 4 + 2) * 64 + lane];
    short8 b3 = sB[(k * 4 + 3) * 64 + lane];

    acc[0] = __builtin_amdgcn_mfma_f32_16x16x32_bf16(af, b0, acc[0], 0, 0, 0);
    acc[1] = __builtin_amdgcn_mfma_f32_16x16x32_bf16(af, b1, acc[1], 0, 0, 0);
    acc[2] = __builtin_amdgcn_mfma_f32_16x16x32_bf16(af, b2, acc[2], 0, 0, 0);
    acc[3] = __builtin_amdgcn_mfma_f32_16x16x32_bf16(af, b3, acc[3], 0, 0, 0);

    af = afn; idA = idB; idB = idC;
  }

  // D layout: col = lane&15, row = (lane>>4)*4 + r
#pragma unroll
  for (int t = 0; t < 4; ++t)
#pragma unroll
    for (int r = 0; r < 4; ++r)
      out[(size_t)(row0 + kg * 4 + r) * COUT + t * 16 + c16] = acc[t][r];
}

// Correct-but-slow fallback if ws is tiny (shouldn't happen).
__global__ void spconv_naive_kernel(const float* __restrict__ feats,
                                    const float* __restrict__ w,
                                    const float* __restrict__ bias,
                                    const int* __restrict__ in_idx,
                                    float* __restrict__ out) {
  int gid = blockIdx.x * blockDim.x + threadIdx.x;
  if (gid >= NROWS * COUT) return;
  int row = gid / COUT, co = gid % COUT;
  float acc = bias[co];
  for (int k = 0; k < KV; ++k) {
    int idx = in_idx[(size_t)k * NROWS + row];
    if (idx < NROWS) {
      const float* fr = feats + (size_t)idx * CIN;
      const float* wk = w + (size_t)k * CIN * COUT + co;
#pragma unroll
      for (int c = 0; c < CIN; ++c) acc += fr[c] * wk[(size_t)c * COUT];
    }
  }
  out[gid] = acc;
}

extern "C" void kernel_launch(void* const* d_in, const int* in_sizes, int n_in,
                              void* d_out, int out_size, void* d_ws, size_t ws_size,
                              hipStream_t stream) {
  const float* feats  = (const float*)d_in[0];
  const float* weight = (const float*)d_in[1];
  const float* bias   = (const float*)d_in[2];
  const int*   in_idx = (const int*)d_in[3];
  float*       out    = (float*)d_out;

  const size_t wsB_bytes = (size_t)KV * 4 * 64 * 16;        // 110592
  const size_t fb_bytes  = (size_t)(NROWS + 1) * CIN * 2;   // 12800064
  short8*         wsB     = (short8*)d_ws;
  unsigned short* featsbf = (unsigned short*)((char*)d_ws + wsB_bytes);

  if (ws_size >= wsB_bytes + fb_bytes) {
    prep_weight_kernel<<<27, 256, 0, stream>>>(weight, wsB);
    prep_feats_kernel<<<((NROWS + 1) * CIN / 8 + 255) / 256, 256, 0, stream>>>(
        feats, (short8*)featsbf);
    // 16 rows per wave, 256 rows per block
    const int blocks = (NROWS + 255) / 256;                  // 782
    spconv_mfma_kernel<<<blocks, 1024, 0, stream>>>(
        featsbf, wsB, bias, in_idx, out);
  } else {
    spconv_naive_kernel<<<(NROWS * COUT + 255) / 256, 256, 0, stream>>>(
        feats, weight, bias, in_idx, out);
  }
}

// Round 3
// 71.659 us; speedup vs baseline: 1.0426x; 1.0426x over previous
//
#include <hip/hip_runtime.h>
#include <cstddef>
#include <cstdint>

#define NROWS 200000
#define CIN   32
#define COUT  64
#define KV    27

typedef __attribute__((ext_vector_type(8))) short  short8;
typedef __attribute__((ext_vector_type(4))) float  f32x4;

// RNE float -> bf16 (inputs finite)
__device__ __forceinline__ unsigned short f2bf(float x) {
  unsigned u = __builtin_bit_cast(unsigned, x);
  u += 0x7FFFu + ((u >> 16) & 1u);
  return (unsigned short)(u >> 16);
}

// Pack weight [27][32][64] f32 -> bf16 B-fragments, mfma_16x16x32 B layout:
// wsB[(k*4+t)*64 + lane][f] = W[k][(lane>>4)*8+f][t*16+(lane&15)]
__global__ void prep_weight_kernel(const float* __restrict__ w,
                                   short8* __restrict__ wsB) {
  int tid = blockIdx.x * blockDim.x + threadIdx.x;   // 27*4*64 = 6912
  if (tid >= KV * 4 * 64) return;
  int lane = tid & 63;
  int t    = (tid >> 6) & 3;
  int k    = tid >> 8;
  int col  = t * 16 + (lane & 15);
  int kin0 = (lane >> 4) * 8;
  short8 v;
#pragma unroll
  for (int f = 0; f < 8; ++f)
    v[f] = (short)f2bf(w[((size_t)k * CIN + kin0 + f) * COUT + col]);
  wsB[tid] = v;
}

// feats f32 [N][32] -> bf16 [N+1][32]; row N (pad) = zeros.
__global__ void prep_feats_kernel(const float* __restrict__ feats,
                                  short8* __restrict__ fb) {
  int i = blockIdx.x * blockDim.x + threadIdx.x;
  const int total8 = (NROWS + 1) * CIN / 8;          // 800004
  if (i >= total8) return;
  short8 v = {0, 0, 0, 0, 0, 0, 0, 0};
  if (i < NROWS * CIN / 8) {
    const f32x4* p = (const f32x4*)feats + (size_t)i * 2;
    f32x4 a = p[0], b = p[1];
#pragma unroll
    for (int f = 0; f < 4; ++f) {
      v[f]     = (short)f2bf(a[f]);
      v[4 + f] = (short)f2bf(b[f]);
    }
  }
  fb[i] = v;
}

// Main: 1 wave = 1 workgroup (64 threads), 64 rows x COUT=64 per wave.
// Gather-latency-bound design: software pipeline with
//   - A-gathers issued 2 iterations ahead (depth-2 window af0/af1 + ag in flight)
//   - idx loaded 4 iterations ahead (rolling 3-stage window)
//   - B-fragments prefetched 1 iteration ahead into registers, issued FIRST in
//     the iteration so the MFMA's s_waitcnt lands at vmcnt(~20) and never
//     drains the k+1/k+2 gathers out of the in-order vmem queue.
// No LDS, no barriers -> fine-grained workgroup scheduling, 12 waves/CU at
// VGPR<=168 (__launch_bounds__(64,3)).
__global__ __launch_bounds__(64, 3)
void spconv_mfma_kernel(const unsigned short* __restrict__ featsbf,
                        const short8* __restrict__ wsB,
                        const float* __restrict__ bias,
                        const int* __restrict__ in_idx,
                        float* __restrict__ out) {
  const int lane = threadIdx.x & 63;
  const int row0 = blockIdx.x << 6;                  // 3125 blocks * 64 rows
  const int c16  = lane & 15;
  const int kg   = lane >> 4;
  const int koff = kg * 8;

  f32x4 acc[4][4];                                   // [m][t]
#pragma unroll
  for (int t = 0; t < 4; ++t) {
    float bv = bias[t * 16 + c16];
    f32x4 bvv = {bv, bv, bv, bv};
#pragma unroll
    for (int m = 0; m < 4; ++m) acc[m][t] = bvv;
  }

  const int*   idxp = in_idx + row0 + c16;
  const short8* bp  = wsB + lane;                    // +(k*4+t)*64

  // ---- prologue: idx k=0..3, gathers k=0,1, B(0) ----
  int i0[4], i1[4], ic[4], id_[4];
#pragma unroll
  for (int m = 0; m < 4; ++m) i0[m]  = idxp[(size_t)0 * NROWS + m * 16];
#pragma unroll
  for (int m = 0; m < 4; ++m) i1[m]  = idxp[(size_t)1 * NROWS + m * 16];
#pragma unroll
  for (int m = 0; m < 4; ++m) ic[m]  = idxp[(size_t)2 * NROWS + m * 16];
#pragma unroll
  for (int m = 0; m < 4; ++m) id_[m] = idxp[(size_t)3 * NROWS + m * 16];

  short8 af0[4], af1[4];
#pragma unroll
  for (int m = 0; m < 4; ++m)
    af0[m] = *(const short8*)(featsbf + (size_t)i0[m] * CIN + koff);
#pragma unroll
  for (int m = 0; m < 4; ++m)
    af1[m] = *(const short8*)(featsbf + (size_t)i1[m] * CIN + koff);

  short8 bc0 = bp[0], bc1 = bp[64], bc2 = bp[128], bc3 = bp[192];

  for (int k = 0; k < KV; ++k) {
    // B(k+1) prefetch -- issued FIRST (keeps MFMA waitcnt away from gathers)
    const int kb = (k + 1 < KV) ? k + 1 : KV - 1;
    short8 bn0 = bp[(kb * 4 + 0) * 64], bn1 = bp[(kb * 4 + 1) * 64],
           bn2 = bp[(kb * 4 + 2) * 64], bn3 = bp[(kb * 4 + 3) * 64];

    // idx(k+4)
    const int ki = (k + 4 < KV) ? k + 4 : KV - 1;
    int it[4];
#pragma unroll
    for (int m = 0; m < 4; ++m) it[m] = idxp[(size_t)ki * NROWS + m * 16];

    // gather A(k+2) using ic = idx(k+2) (arrived: loaded 2 iters ago)
    short8 ag[4];
#pragma unroll
    for (int m = 0; m < 4; ++m)
      ag[m] = *(const short8*)(featsbf + (size_t)ic[m] * CIN + koff);

    // MFMA on A(k), B(k) -- both landed >=1 full iteration ago
#pragma unroll
    for (int m = 0; m < 4; ++m) {
      acc[m][0] = __builtin_amdgcn_mfma_f32_16x16x32_bf16(af0[m], bc0, acc[m][0], 0, 0, 0);
      acc[m][1] = __builtin_amdgcn_mfma_f32_16x16x32_bf16(af0[m], bc1, acc[m][1], 0, 0, 0);
      acc[m][2] = __builtin_amdgcn_mfma_f32_16x16x32_bf16(af0[m], bc2, acc[m][2], 0, 0, 0);
      acc[m][3] = __builtin_amdgcn_mfma_f32_16x16x32_bf16(af0[m], bc3, acc[m][3], 0, 0, 0);
    }

    // rotate windows (register renames after regalloc)
#pragma unroll
    for (int m = 0; m < 4; ++m) {
      af0[m] = af1[m]; af1[m] = ag[m];
      ic[m] = id_[m]; id_[m] = it[m];
    }
    bc0 = bn0; bc1 = bn1; bc2 = bn2; bc3 = bn3;
  }

  // D layout: col = t*16 + (lane&15), row = (lane>>4)*4 + r
#pragma unroll
  for (int m = 0; m < 4; ++m)
#pragma unroll
    for (int t = 0; t < 4; ++t)
#pragma unroll
      for (int r = 0; r < 4; ++r)
        out[(size_t)(row0 + m * 16 + kg * 4 + r) * COUT + t * 16 + c16] = acc[m][t][r];
}

// Correct-but-slow fallback if ws is tiny (shouldn't happen).
__global__ void spconv_naive_kernel(const float* __restrict__ feats,
                                    const float* __restrict__ w,
                                    const float* __restrict__ bias,
                                    const int* __restrict__ in_idx,
                                    float* __restrict__ out) {
  int gid = blockIdx.x * blockDim.x + threadIdx.x;
  if (gid >= NROWS * COUT) return;
  int row = gid / COUT, co = gid % COUT;
  float acc = bias[co];
  for (int k = 0; k < KV; ++k) {
    int idx = in_idx[(size_t)k * NROWS + row];
    if (idx < NROWS) {
      const float* fr = feats + (size_t)idx * CIN;
      const float* wk = w + (size_t)k * CIN * COUT + co;
#pragma unroll
      for (int c = 0; c < CIN; ++c) acc += fr[c] * wk[(size_t)c * COUT];
    }
  }
  out[gid] = acc;
}

extern "C" void kernel_launch(void* const* d_in, const int* in_sizes, int n_in,
                              void* d_out, int out_size, void* d_ws, size_t ws_size,
                              hipStream_t stream) {
  const float* feats  = (const float*)d_in[0];
  const float* weight = (const float*)d_in[1];
  const float* bias   = (const float*)d_in[2];
  const int*   in_idx = (const int*)d_in[3];
  float*       out    = (float*)d_out;

  const size_t wsB_bytes = (size_t)KV * 4 * 64 * 16;        // 110592
  const size_t fb_bytes  = (size_t)(NROWS + 1) * CIN * 2;   // 12800064
  short8*         wsB     = (short8*)d_ws;
  unsigned short* featsbf = (unsigned short*)((char*)d_ws + wsB_bytes);

  if (ws_size >= wsB_bytes + fb_bytes) {
    prep_weight_kernel<<<27, 256, 0, stream>>>(weight, wsB);
    prep_feats_kernel<<<((NROWS + 1) * CIN / 8 + 255) / 256, 256, 0, stream>>>(
        feats, (short8*)featsbf);
    const int blocks = NROWS / 64;                           // 3125 waves
    spconv_mfma_kernel<<<blocks, 64, 0, stream>>>(
        featsbf, wsB, bias, in_idx, out);
  } else {
    spconv_naive_kernel<<<(NROWS * COUT + 255) / 256, 256, 0, stream>>>(
        feats, weight, bias, in_idx, out);
  }
}

// Round 4
// 59.588 us; speedup vs baseline: 1.2538x; 1.2026x over previous
//
#include <hip/hip_runtime.h>
#include <cstddef>
#include <cstdint>

#define NROWS 200000
#define CIN   32
#define COUT  64
#define KV    27

typedef __attribute__((ext_vector_type(8))) short  short8;
typedef __attribute__((ext_vector_type(4))) float  f32x4;

// RNE float -> bf16 (inputs finite)
__device__ __forceinline__ unsigned short f2bf(float x) {
  unsigned u = __builtin_bit_cast(unsigned, x);
  u += 0x7FFFu + ((u >> 16) & 1u);
  return (unsigned short)(u >> 16);
}

// Pack weight [27][32][64] f32 -> bf16 B-fragments, mfma_16x16x32 B layout:
// wsB[(k*4+t)*64 + lane][f] = W[k][(lane>>4)*8+f][t*16+(lane&15)]
__global__ void prep_weight_kernel(const float* __restrict__ w,
                                   short8* __restrict__ wsB) {
  int tid = blockIdx.x * blockDim.x + threadIdx.x;   // 27*4*64 = 6912
  if (tid >= KV * 4 * 64) return;
  int lane = tid & 63;
  int t    = (tid >> 6) & 3;
  int k    = tid >> 8;
  int col  = t * 16 + (lane & 15);
  int kin0 = (lane >> 4) * 8;
  short8 v;
#pragma unroll
  for (int f = 0; f < 8; ++f)
    v[f] = (short)f2bf(w[((size_t)k * CIN + kin0 + f) * COUT + col]);
  wsB[tid] = v;
}

// feats f32 [N][32] -> bf16 [N+1][32]; row N (pad) = zeros.
__global__ void prep_feats_kernel(const float* __restrict__ feats,
                                  short8* __restrict__ fb) {
  int i = blockIdx.x * blockDim.x + threadIdx.x;
  const int total8 = (NROWS + 1) * CIN / 8;          // 800004
  if (i >= total8) return;
  short8 v = {0, 0, 0, 0, 0, 0, 0, 0};
  if (i < NROWS * CIN / 8) {
    const f32x4* p = (const f32x4*)feats + (size_t)i * 2;
    f32x4 a = p[0], b = p[1];
#pragma unroll
    for (int f = 0; f < 4; ++f) {
      v[f]     = (short)f2bf(a[f]);
      v[4 + f] = (short)f2bf(b[f]);
    }
  }
  fb[i] = v;
}

// Main (round-1 structure + XCD-aware bijective chunked block swizzle).
// 256-thread blocks, 4 waves; each wave: 64 rows (Mw=4) x COUT=64.
// Swizzle: default dispatch round-robins blocks across the 8 XCDs; remapping
// so each XCD gets a CONTIGUOUS chunk of row-tiles shrinks the per-XCD L2
// gather working set from 12.8 MB (whole featsbf) to ~0.6 MB (rows are
// spatially sorted; the 27 neighbor rows lie within ~±1300 of j) -> L2 hits.
__global__ __launch_bounds__(256)
void spconv_mfma_kernel(const unsigned short* __restrict__ featsbf,
                        const short8* __restrict__ wsB,
                        const float* __restrict__ bias,
                        const int* __restrict__ in_idx,
                        float* __restrict__ out) {
  // bijective chunked swizzle for nwg=782 over 8 XCDs: q=97, r=6
  const int bid  = blockIdx.x;
  const int xcd  = bid & 7;
  const int i    = bid >> 3;
  const int sbid = (xcd < 6) ? xcd * 98 + i : 6 * 98 + (xcd - 6) * 97 + i;

  const int lane = threadIdx.x & 63;
  const int wid  = (sbid << 2) + (int)(threadIdx.x >> 6); // wave id in row space
  if (wid >= NROWS / 64) return;                          // 3125 active waves
  const int row0 = wid << 6;
  const int c16  = lane & 15;
  const int kg   = lane >> 4;
  const int koff = kg * 8;

  f32x4 acc[4][4];                                   // [m][t]
#pragma unroll
  for (int t = 0; t < 4; ++t) {
    float bv = bias[t * 16 + c16];
    f32x4 bvv = {bv, bv, bv, bv};
#pragma unroll
    for (int m = 0; m < 4; ++m) acc[m][t] = bvv;
  }

  const int*    idxp = in_idx + row0 + c16;
  const short8* bp   = wsB + lane;

  for (int k = 0; k < KV; ++k) {
    // idx loads for all 4 m-tiles first, then all 4 gathers -> 4 independent
    // gather lines in flight per wave while MFMAs of this k run.
    int idx[4];
#pragma unroll
    for (int m = 0; m < 4; ++m)
      idx[m] = idxp[(size_t)k * NROWS + m * 16];

    short8 bfr[4];
#pragma unroll
    for (int t = 0; t < 4; ++t) bfr[t] = bp[(k * 4 + t) * 64];

    short8 afr[4];
#pragma unroll
    for (int m = 0; m < 4; ++m)
      afr[m] = *(const short8*)(featsbf + (size_t)idx[m] * CIN + koff);

#pragma unroll
    for (int m = 0; m < 4; ++m) {
      acc[m][0] = __builtin_amdgcn_mfma_f32_16x16x32_bf16(afr[m], bfr[0], acc[m][0], 0, 0, 0);
      acc[m][1] = __builtin_amdgcn_mfma_f32_16x16x32_bf16(afr[m], bfr[1], acc[m][1], 0, 0, 0);
      acc[m][2] = __builtin_amdgcn_mfma_f32_16x16x32_bf16(afr[m], bfr[2], acc[m][2], 0, 0, 0);
      acc[m][3] = __builtin_amdgcn_mfma_f32_16x16x32_bf16(afr[m], bfr[3], acc[m][3], 0, 0, 0);
    }
  }

  // D layout: col = t*16 + (lane&15), row = (lane>>4)*4 + r
#pragma unroll
  for (int m = 0; m < 4; ++m)
#pragma unroll
    for (int t = 0; t < 4; ++t)
#pragma unroll
      for (int r = 0; r < 4; ++r)
        out[(size_t)(row0 + m * 16 + kg * 4 + r) * COUT + t * 16 + c16] = acc[m][t][r];
}

// Correct-but-slow fallback if ws is tiny (shouldn't happen).
__global__ void spconv_naive_kernel(const float* __restrict__ feats,
                                    const float* __restrict__ w,
                                    const float* __restrict__ bias,
                                    const int* __restrict__ in_idx,
                                    float* __restrict__ out) {
  int gid = blockIdx.x * blockDim.x + threadIdx.x;
  if (gid >= NROWS * COUT) return;
  int row = gid / COUT, co = gid % COUT;
  float acc = bias[co];
  for (int k = 0; k < KV; ++k) {
    int idx = in_idx[(size_t)k * NROWS + row];
    if (idx < NROWS) {
      const float* fr = feats + (size_t)idx * CIN;
      const float* wk = w + (size_t)k * CIN * COUT + co;
#pragma unroll
      for (int c = 0; c < CIN; ++c) acc += fr[c] * wk[(size_t)c * COUT];
    }
  }
  out[gid] = acc;
}

extern "C" void kernel_launch(void* const* d_in, const int* in_sizes, int n_in,
                              void* d_out, int out_size, void* d_ws, size_t ws_size,
                              hipStream_t stream) {
  const float* feats  = (const float*)d_in[0];
  const float* weight = (const float*)d_in[1];
  const float* bias   = (const float*)d_in[2];
  const int*   in_idx = (const int*)d_in[3];
  float*       out    = (float*)d_out;

  const size_t wsB_bytes = (size_t)KV * 4 * 64 * 16;        // 110592
  const size_t fb_bytes  = (size_t)(NROWS + 1) * CIN * 2;   // 12800064
  short8*         wsB     = (short8*)d_ws;
  unsigned short* featsbf = (unsigned short*)((char*)d_ws + wsB_bytes);

  if (ws_size >= wsB_bytes + fb_bytes) {
    prep_weight_kernel<<<27, 256, 0, stream>>>(weight, wsB);
    prep_feats_kernel<<<((NROWS + 1) * CIN / 8 + 255) / 256, 256, 0, stream>>>(
        feats, (short8*)featsbf);
    const int blocks = (NROWS / 64 + 3) / 4;                 // 782
    spconv_mfma_kernel<<<blocks, 256, 0, stream>>>(
        featsbf, wsB, bias, in_idx, out);
  } else {
    spconv_naive_kernel<<<(NROWS * COUT + 255) / 256, 256, 0, stream>>>(
        feats, weight, bias, in_idx, out);
  }
}

// Round 5
// 58.157 us; speedup vs baseline: 1.2846x; 1.0246x over previous
//
#include <hip/hip_runtime.h>
#include <cstddef>
#include <cstdint>

#define NROWS  200000
#define CIN    32
#define COUT   64
#define KV     27
#define NWAVES (NROWS / 64)   // 3125

typedef __attribute__((ext_vector_type(8))) short  short8;
typedef __attribute__((ext_vector_type(4))) float  f32x4;

// RNE float -> bf16 (inputs finite)
__device__ __forceinline__ unsigned short f2bf(float x) {
  unsigned u = __builtin_bit_cast(unsigned, x);
  u += 0x7FFFu + ((u >> 16) & 1u);
  return (unsigned short)(u >> 16);
}

// Pack weight [27][32][64] f32 -> bf16 B-fragments, mfma_16x16x32 B layout:
// wsB[(k*4+t)*64 + lane][f] = W[k][(lane>>4)*8+f][t*16+(lane&15)]
__global__ void prep_weight_kernel(const float* __restrict__ w,
                                   short8* __restrict__ wsB) {
  int tid = blockIdx.x * blockDim.x + threadIdx.x;   // 27*4*64 = 6912
  if (tid >= KV * 4 * 64) return;
  int lane = tid & 63;
  int t    = (tid >> 6) & 3;
  int k    = tid >> 8;
  int col  = t * 16 + (lane & 15);
  int kin0 = (lane >> 4) * 8;
  short8 v;
#pragma unroll
  for (int f = 0; f < 8; ++f)
    v[f] = (short)f2bf(w[((size_t)k * CIN + kin0 + f) * COUT + col]);
  wsB[tid] = v;
}

// feats f32 [N][32] -> bf16 [N+1][32]; row N (pad) = zeros.
__global__ void prep_feats_kernel(const float* __restrict__ feats,
                                  short8* __restrict__ fb) {
  int i = blockIdx.x * blockDim.x + threadIdx.x;
  const int total8 = (NROWS + 1) * CIN / 8;          // 800004
  if (i >= total8) return;
  short8 v = {0, 0, 0, 0, 0, 0, 0, 0};
  if (i < NROWS * CIN / 8) {
    const f32x4* p = (const f32x4*)feats + (size_t)i * 2;
    f32x4 a = p[0], b = p[1];
#pragma unroll
    for (int f = 0; f < 4; ++f) {
      v[f]     = (short)f2bf(a[f]);
      v[4 + f] = (short)f2bf(b[f]);
    }
  }
  fb[i] = v;
}

// Main (R1 structure + idx staged through LDS).
// 256-thread blocks, 4 waves; each wave: 64 rows (Mw=4) x COUT=64.
// Prologue: the wave's whole 27x64 idx block is fetched as 27 INDEPENDENT
// coalesced loads (one overlapped HBM round-trip instead of 27 serial cold
// misses on the k-loop critical path) and parked in a per-wave LDS region.
// k-loop: idx via ds_read broadcast (prefetched 1 iter ahead), so the only
// exposed latency per iteration is the feats gather itself.
__global__ __launch_bounds__(256, 4)
void spconv_mfma_kernel(const unsigned short* __restrict__ featsbf,
                        const short8* __restrict__ wsB,
                        const float* __restrict__ bias,
                        const int* __restrict__ in_idx,
                        float* __restrict__ out) {
  __shared__ int sIdx[4][KV][64];                    // 27,648 B

  const int tid  = threadIdx.x;
  const int lane = tid & 63;
  const int w    = tid >> 6;
  const int wid  = (int)blockIdx.x * 4 + w;
  if (wid >= NWAVES) return;
  const int row0 = wid << 6;

  // ---- stage this wave's idx block into LDS (per-wave region, no barrier) --
  {
    int tmp[KV];
#pragma unroll
    for (int k = 0; k < KV; ++k)
      tmp[k] = in_idx[(size_t)k * NROWS + row0 + lane];
#pragma unroll
    for (int k = 0; k < KV; ++k)
      sIdx[w][k][lane] = tmp[k];
  }

  const int c16  = lane & 15;
  const int kg   = lane >> 4;
  const int koff = kg * 8;

  f32x4 acc[4][4];                                   // [m][t]
#pragma unroll
  for (int t = 0; t < 4; ++t) {
    float bv = bias[t * 16 + c16];
    f32x4 bvv = {bv, bv, bv, bv};
#pragma unroll
    for (int m = 0; m < 4; ++m) acc[m][t] = bvv;
  }

  const short8* bp = wsB + lane;

  // idx for k=0 (broadcast ds_read: 4 lanes same address -> free)
  int idxc[4], idxn[4];
#pragma unroll
  for (int m = 0; m < 4; ++m) idxc[m] = sIdx[w][0][m * 16 + c16];

  for (int k = 0; k < KV; ++k) {
    // prefetch idx(k+1) from LDS (off the global-latency path entirely)
    const int kn = (k + 1 < KV) ? k + 1 : KV - 1;
#pragma unroll
    for (int m = 0; m < 4; ++m) idxn[m] = sIdx[w][kn][m * 16 + c16];

    short8 bfr[4];
#pragma unroll
    for (int t = 0; t < 4; ++t) bfr[t] = bp[(k * 4 + t) * 64];

    short8 afr[4];
#pragma unroll
    for (int m = 0; m < 4; ++m)
      afr[m] = *(const short8*)(featsbf + (size_t)idxc[m] * CIN + koff);

#pragma unroll
    for (int m = 0; m < 4; ++m) {
      acc[m][0] = __builtin_amdgcn_mfma_f32_16x16x32_bf16(afr[m], bfr[0], acc[m][0], 0, 0, 0);
      acc[m][1] = __builtin_amdgcn_mfma_f32_16x16x32_bf16(afr[m], bfr[1], acc[m][1], 0, 0, 0);
      acc[m][2] = __builtin_amdgcn_mfma_f32_16x16x32_bf16(afr[m], bfr[2], acc[m][2], 0, 0, 0);
      acc[m][3] = __builtin_amdgcn_mfma_f32_16x16x32_bf16(afr[m], bfr[3], acc[m][3], 0, 0, 0);
    }

#pragma unroll
    for (int m = 0; m < 4; ++m) idxc[m] = idxn[m];
  }

  // D layout: col = t*16 + (lane&15), row = (lane>>4)*4 + r
#pragma unroll
  for (int m = 0; m < 4; ++m)
#pragma unroll
    for (int t = 0; t < 4; ++t)
#pragma unroll
      for (int r = 0; r < 4; ++r)
        out[(size_t)(row0 + m * 16 + kg * 4 + r) * COUT + t * 16 + c16] = acc[m][t][r];
}

// Correct-but-slow fallback if ws is tiny (shouldn't happen).
__global__ void spconv_naive_kernel(const float* __restrict__ feats,
                                    const float* __restrict__ w,
                                    const float* __restrict__ bias,
                                    const int* __restrict__ in_idx,
                                    float* __restrict__ out) {
  int gid = blockIdx.x * blockDim.x + threadIdx.x;
  if (gid >= NROWS * COUT) return;
  int row = gid / COUT, co = gid % COUT;
  float acc = bias[co];
  for (int k = 0; k < KV; ++k) {
    int idx = in_idx[(size_t)k * NROWS + row];
    if (idx < NROWS) {
      const float* fr = feats + (size_t)idx * CIN;
      const float* wk = w + (size_t)k * CIN * COUT + co;
#pragma unroll
      for (int c = 0; c < CIN; ++c) acc += fr[c] * wk[(size_t)c * COUT];
    }
  }
  out[gid] = acc;
}

extern "C" void kernel_launch(void* const* d_in, const int* in_sizes, int n_in,
                              void* d_out, int out_size, void* d_ws, size_t ws_size,
                              hipStream_t stream) {
  const float* feats  = (const float*)d_in[0];
  const float* weight = (const float*)d_in[1];
  const float* bias   = (const float*)d_in[2];
  const int*   in_idx = (const int*)d_in[3];
  float*       out    = (float*)d_out;

  const size_t wsB_bytes = (size_t)KV * 4 * 64 * 16;        // 110592
  const size_t fb_bytes  = (size_t)(NROWS + 1) * CIN * 2;   // 12800064
  short8*         wsB     = (short8*)d_ws;
  unsigned short* featsbf = (unsigned short*)((char*)d_ws + wsB_bytes);

  if (ws_size >= wsB_bytes + fb_bytes) {
    prep_weight_kernel<<<27, 256, 0, stream>>>(weight, wsB);
    prep_feats_kernel<<<((NROWS + 1) * CIN / 8 + 255) / 256, 256, 0, stream>>>(
        feats, (short8*)featsbf);
    const int blocks = (NWAVES + 3) / 4;                     // 782
    spconv_mfma_kernel<<<blocks, 256, 0, stream>>>(
        featsbf, wsB, bias, in_idx, out);
  } else {
    spconv_naive_kernel<<<(NROWS * COUT + 255) / 256, 256, 0, stream>>>(
        feats, weight, bias, in_idx, out);
  }
}